// Round 3
// baseline (161.935 us; speedup 1.0000x reference)
//
#include <hip/hip_runtime.h>
#include <hip/hip_bf16.h>

#define DIN  256
#define DOUT 256
#define KNEI 16

typedef __attribute__((ext_vector_type(4))) float f32x4;
typedef __attribute__((ext_vector_type(8))) short bf16x8;
typedef __attribute__((ext_vector_type(4))) short bf16x4;

__device__ __forceinline__ short f2bf(float f) {
    unsigned int u;
    __builtin_memcpy(&u, &f, 4);
    unsigned int r = (u + 0x7fffu + ((u >> 16) & 1u)) >> 16;
    return (short)r;
}

__device__ __forceinline__ float bf2f(short s) {
    unsigned int u = ((unsigned int)(unsigned short)s) << 16;
    float f;
    __builtin_memcpy(&f, &u, 4);
    return f;
}

// ---------------------------------------------------------------------------
// K0: pack W into bf16 MFMA fragment layout (blocks 0..31) + zero the src
// bitmap (blocks 32..). Fragment (cb, kb): lane l holds
// W[col = cb*16 + (l&15)][k = kb*32 + (l>>4)*8 + j], j=0..7.
// Stored at Wp + ((cb*8 + kb)*64 + lane)*8 bf16.
// ---------------------------------------------------------------------------
__global__ __launch_bounds__(256) void pack_w_kernel(
        const float* __restrict__ W, short* __restrict__ Wp,
        unsigned char* __restrict__ bm, int N) {
    if (blockIdx.x < 32) {
        int gid  = blockIdx.x * 256 + threadIdx.x;
        int lane = gid & 63;
        int frag = gid >> 6;                     // 0..127
        int kb   = frag & 7;
        int cb   = frag >> 3;
        int col  = cb * 16 + (lane & 15);
        int k0   = kb * 32 + (lane >> 4) * 8;
        const float* src = W + (size_t)col * DIN + k0;
        bf16x8 v;
#pragma unroll
        for (int j = 0; j < 8; ++j) v[j] = f2bf(src[j]);
        *((bf16x8*)Wp + (size_t)frag * 64 + lane) = v;
    } else {
        int i = (blockIdx.x - 32) * 256 + threadIdx.x;
        if (i < N) bm[i] = 0;
    }
}

__global__ __launch_bounds__(256) void set_bm_kernel(
        const int* __restrict__ src_idx, unsigned char* __restrict__ bm, int S) {
    int s = blockIdx.x * 256 + threadIdx.x;
    if (s < S) bm[src_idx[s]] = 1;
}

// ---------------------------------------------------------------------------
// K1: supports = wv @ W^T + b   (bf16 MFMA, f32 accumulate)
// One wave = 16 rows x 64 cols. All 16 A-loads + 32 W-fragment loads are
// issued up front into registers (issue order == consumption order), one
// vmcnt unwind, then 32 pure-register MFMAs. 4 waves/block share the same
// 16 rows (A re-read served by L1). No LDS, no barriers.
// f32 out store skipped for src rows (bitmap) -- aggregate overwrites them.
// ---------------------------------------------------------------------------
__global__ __launch_bounds__(256) void gemm_kernel(
        const float* __restrict__ A, const short* __restrict__ Wp,
        const float* __restrict__ bias, float* __restrict__ out,
        short* __restrict__ out_bf, const unsigned char* __restrict__ bm,
        int M, int use_bm) {
    const int tid  = threadIdx.x;
    const int wid  = tid >> 6;                  // col-block 0..3
    const int lane = tid & 63;
    const int row0 = blockIdx.x * 16;
    if (row0 >= M) return;

    const int rraw = row0 + (lane & 15);
    const int r    = (rraw < M) ? rraw : (M - 1);
    const int g    = lane >> 4;

    // ---- issue A slab loads (16 x 16B/lane, HBM) ----
    const float* arow = A + (size_t)r * DIN + g * 8;
    f32x4 araw[16];
#pragma unroll
    for (int kb = 0; kb < 8; ++kb) {
        araw[2 * kb]     = *(const f32x4*)(arow + kb * 32);
        araw[2 * kb + 1] = *(const f32x4*)(arow + kb * 32 + 4);
    }

    // ---- issue all 32 W fragment loads (L2-resident), consumption order ----
    const bf16x8* wp = (const bf16x8*)Wp;
    bf16x8 wfrag[8][4];
#pragma unroll
    for (int kb = 0; kb < 8; ++kb) {
#pragma unroll
        for (int j = 0; j < 4; ++j) {
            int cb = wid * 4 + j;
            wfrag[kb][j] = wp[(size_t)(cb * 8 + kb) * 64 + lane];
        }
    }

    // ---- convert A to bf16 fragments (waits only on A's vmcnt) ----
    bf16x8 afrag[8];
#pragma unroll
    for (int kb = 0; kb < 8; ++kb) {
#pragma unroll
        for (int j = 0; j < 4; ++j) {
            afrag[kb][j]     = f2bf(araw[2 * kb][j]);
            afrag[kb][4 + j] = f2bf(araw[2 * kb + 1][j]);
        }
    }

    f32x4 acc[4];
#pragma unroll
    for (int j = 0; j < 4; ++j) acc[j] = f32x4{0.f, 0.f, 0.f, 0.f};

#pragma unroll
    for (int kb = 0; kb < 8; ++kb) {
#pragma unroll
        for (int j = 0; j < 4; ++j)
            acc[j] = __builtin_amdgcn_mfma_f32_16x16x32_bf16(
                wfrag[kb][j], afrag[kb], acc[j], 0, 0, 0);
    }

    // ---- epilogue: lane holds rows=lane&15, douts c0..c0+4 per j ----
    const bool wr = (rraw < M);
    const bool store_f32 = wr && (!use_bm || bm[r] == 0);
    float* orow = out    + (size_t)r * DOUT;
    short* brow = out_bf + (size_t)r * DOUT;
#pragma unroll
    for (int j = 0; j < 4; ++j) {
        int c0 = wid * 64 + j * 16 + g * 4;
        f32x4 bv = *(const f32x4*)(bias + c0);
        f32x4 v  = acc[j] + bv;
        bf16x4 h;
#pragma unroll
        for (int q = 0; q < 4; ++q) h[q] = f2bf(v[q]);
        if (wr) *(bf16x4*)(brow + c0) = h;
        if (store_f32) *(f32x4*)(orow + c0) = v;
    }
}

// ---------------------------------------------------------------------------
// K2 (fused): per source row s (one wave):
//   sv  = sup_bf[src_idx[s]]
//   agg = sum_k mask[s,k] * sup_bf[neigh[s,k]]
//   out[src_idx[s]] = sv + leaky(agg + sv)
// Race-free: src_idx unique; all gathers hit the immutable shadow.
// ---------------------------------------------------------------------------
__global__ __launch_bounds__(256) void aggregate_fused_kernel(
        const short* __restrict__ sup_bf, const int* __restrict__ src_idx,
        const int* __restrict__ neighs, const float* __restrict__ mask,
        float* __restrict__ out, int S) {
    int s = blockIdx.x * 4 + (threadIdx.x >> 6);
    if (s >= S) return;
    s = __builtin_amdgcn_readfirstlane(s);
    const int lane = threadIdx.x & 63;
    const int c4   = lane * 4;

    f32x4 acc = {0.f, 0.f, 0.f, 0.f};
#pragma unroll
    for (int k = 0; k < KNEI; ++k) {
        int   idx = neighs[(size_t)s * KNEI + k];
        float m   = mask[(size_t)s * KNEI + k];
        bf16x4 v = *(const bf16x4*)(sup_bf + (size_t)idx * DOUT + c4);
#pragma unroll
        for (int j = 0; j < 4; ++j) acc[j] += m * bf2f(v[j]);
    }

    int srow = src_idx[s];
    bf16x4 svh = *(const bf16x4*)(sup_bf + (size_t)srow * DOUT + c4);
    f32x4 res;
#pragma unroll
    for (int j = 0; j < 4; ++j) {
        float sv = bf2f(svh[j]);
        float o  = acc[j] + sv;
        o = (o >= 0.f) ? o : 0.2f * o;
        res[j] = sv + o;
    }
    *(f32x4*)(out + (size_t)srow * DOUT + c4) = res;
}

// ---------------------------------------------------------------------------
// Fallback path (ws too small for bf16 shadow).
// ---------------------------------------------------------------------------
__global__ __launch_bounds__(256) void aggregate_f32_kernel(
        const float* __restrict__ supports, const int* __restrict__ src_idx,
        const int* __restrict__ neighs, const float* __restrict__ mask,
        float* __restrict__ outrows, int S) {
    int s = blockIdx.x * 4 + (threadIdx.x >> 6);
    if (s >= S) return;
    s = __builtin_amdgcn_readfirstlane(s);
    const int lane = threadIdx.x & 63;
    const int c4   = lane * 4;
    f32x4 acc = {0.f, 0.f, 0.f, 0.f};
#pragma unroll
    for (int k = 0; k < KNEI; ++k) {
        int   idx = neighs[(size_t)s * KNEI + k];
        float m   = mask[(size_t)s * KNEI + k];
        f32x4 v = *(const f32x4*)(supports + (size_t)idx * DOUT + c4);
#pragma unroll
        for (int j = 0; j < 4; ++j) acc[j] += m * v[j];
    }
    int srow = src_idx[s];
    f32x4 sv = *(const f32x4*)(supports + (size_t)srow * DOUT + c4);
    f32x4 res;
#pragma unroll
    for (int j = 0; j < 4; ++j) {
        float o = acc[j] + sv[j];
        o = (o >= 0.f) ? o : 0.2f * o;
        res[j] = sv[j] + o;
    }
    *(f32x4*)(outrows + (size_t)s * DOUT + c4) = res;
}

__global__ __launch_bounds__(256) void scatter_kernel(
        const float* __restrict__ outrows, const int* __restrict__ src_idx,
        float* __restrict__ out, int S) {
    int gid = blockIdx.x * 256 + threadIdx.x;
    int s   = gid >> 6;
    if (s >= S) return;
    int lane = gid & 63;
    int row  = src_idx[s];
    *(f32x4*)(out + (size_t)row * DOUT + lane * 4) =
        *(const f32x4*)(outrows + (size_t)s * DOUT + lane * 4);
}

extern "C" void kernel_launch(void* const* d_in, const int* in_sizes, int n_in,
                              void* d_out, int out_size, void* d_ws, size_t ws_size,
                              hipStream_t stream) {
    (void)n_in; (void)out_size;
    const float* wv     = (const float*)d_in[0];
    const int*   src_i  = (const int*)d_in[1];
    const int*   neighs = (const int*)d_in[2];
    const float* mask   = (const float*)d_in[3];
    const float* W      = (const float*)d_in[4];
    const float* bias   = (const float*)d_in[5];
    float* out = (float*)d_out;

    const int N = in_sizes[0] / DIN;   // 100000
    const int S = in_sizes[1];         // 50000

    // ws layout: [Wp bf16 128KB][bm N bytes][shadow bf16 N*256 | outrows f32]
    char*  ws      = (char*)d_ws;
    size_t sz_wp   = (size_t)DOUT * DIN * 2;
    size_t off_bm  = (sz_wp + 1023) & ~(size_t)1023;
    size_t off_buf = (off_bm + (size_t)N + 1023) & ~(size_t)1023;
    short*         Wp      = (short*)ws;
    unsigned char* bm      = (unsigned char*)(ws + off_bm);
    short*         sup_bf  = (short*)(ws + off_buf);
    float*         outrows = (float*)(ws + off_buf);
    int fused = (ws_size >= off_buf + (size_t)N * DOUT * 2) ? 1 : 0;

    int zblocks = (N + 255) / 256;
    pack_w_kernel<<<32 + zblocks, 256, 0, stream>>>(W, Wp, bm, N);
    if (fused)
        set_bm_kernel<<<(S + 255) / 256, 256, 0, stream>>>(src_i, bm, S);

    int mblocks = (N + 15) / 16;
    gemm_kernel<<<mblocks, 256, 0, stream>>>(
        wv, Wp, bias, out, sup_bf, bm, N, fused);

    if (fused) {
        aggregate_fused_kernel<<<(S + 3) / 4, 256, 0, stream>>>(
            sup_bf, src_i, neighs, mask, out, S);
    } else {
        aggregate_f32_kernel<<<(S + 3) / 4, 256, 0, stream>>>(
            out, src_i, neighs, mask, outrows, S);
        scatter_kernel<<<((size_t)S * 64 + 255) / 256, 256, 0, stream>>>(
            outrows, src_i, out, S);
    }
}